// Round 10
// baseline (382.789 us; speedup 1.0000x reference)
//
#include <hip/hip_runtime.h>
#include <hip/hip_bf16.h>

typedef unsigned short ushort;
typedef unsigned int uint;
typedef __bf16 bf16x8 __attribute__((ext_vector_type(8)));
typedef float f32x4 __attribute__((ext_vector_type(4)));
typedef uint uint4v __attribute__((ext_vector_type(4)));
typedef uint uint2v __attribute__((ext_vector_type(2)));

#define CI 128
#define HIN 64
#define WIN 64
#define CO 256
#define HO 62
#define WO 62
#define NB 32
#define KTOT 1152            // 9 taps * 128 ci   (k = tap*128 + ci in repacked order)
#define PIXIMG 3844          // 62*62
#define NPIX 123008          // 32*3844, divisible by 128
#define XIMG 524288          // 128*64*64
#define BK 64
#define NKT 18               // 1152/64

__device__ __forceinline__ ushort f2bf(float f) {
  uint u = __builtin_bit_cast(uint, f);
  u += 0x7fffu + ((u >> 16) & 1u);   // RNE; inputs are finite Gaussians
  return (ushort)(u >> 16);
}

// ---------------- fused prep ----------------
// blocks 0..2047:  x[n][ci][h][w] fp32 -> x2[n][h][w][ci] bf16   (n = b>>6, h = b&63)
// blocks 2048..2303: w[co][ci][3][3] fp32 -> w2[co][tap*128+ci] bf16 (co = b-2048)
#define XPAD 132   // floats per w-row in LDS; 132*4B = 16B-aligned rows
__global__ __launch_bounds__(256) void repack_fused_kernel(const float* __restrict__ x,
                                                           const float* __restrict__ w,
                                                           ushort* __restrict__ x2,
                                                           ushort* __restrict__ w2) {
  __shared__ float t[WIN * XPAD];           // 33792 B
  const int b   = blockIdx.x;
  const int tid = threadIdx.x;

  if (b >= 2048) {                          // ---- weight repack ----
    const int co = b - 2048;
    for (int idx = tid; idx < KTOT; idx += 256) {
      const int tp = idx >> 7;              // tap 0..8
      const int ci = idx & 127;
      w2[co * KTOT + idx] = f2bf(w[(co * CI + ci) * 9 + tp]);
    }
    return;
  }

  const int n = b >> 6;                     // 0..31
  const int h = b & 63;                     // 0..63
  const float* src = x + ((size_t)n * CI * HIN + h) * WIN;   // + ci*4096 + w
  #pragma unroll
  for (int it = 0; it < 8; ++it) {
    const int idx = it * 256 + tid;         // 0..2047
    const int ci  = idx >> 4;               // 0..127
    const int w4  = (idx & 15) * 4;         // 0..60
    const float4 v = *reinterpret_cast<const float4*>(src + (size_t)ci * (HIN * WIN) + w4);
    t[(w4 + 0) * XPAD + ci] = v.x;
    t[(w4 + 1) * XPAD + ci] = v.y;
    t[(w4 + 2) * XPAD + ci] = v.z;
    t[(w4 + 3) * XPAD + ci] = v.w;
  }
  __syncthreads();
  ushort* dst = x2 + ((size_t)(n * HIN + h) * WIN) * CI;
  #pragma unroll
  for (int it = 0; it < 4; ++it) {
    const int idx = it * 256 + tid;         // 0..1023
    const int wq  = idx >> 4;               // 0..63
    const int cig = idx & 15;               // 0..15
    const float* p = &t[wq * XPAD + cig * 8];
    uint4v q;
    q[0] = (uint)f2bf(p[0]) | ((uint)f2bf(p[1]) << 16);
    q[1] = (uint)f2bf(p[2]) | ((uint)f2bf(p[3]) << 16);
    q[2] = (uint)f2bf(p[4]) | ((uint)f2bf(p[5]) << 16);
    q[3] = (uint)f2bf(p[6]) | ((uint)f2bf(p[7]) << 16);
    *reinterpret_cast<uint4v*>(dst + (size_t)wq * CI + cig * 8) = q;
  }
}

// ---------------- main: implicit GEMM, all staging via global_load_lds (R4 structure) ----
// block = 256 thr, 128co x 128pix tile, 32 KiB LDS -> 5 blocks/CU (160 KiB exactly)
__global__ __launch_bounds__(256, 5)
void conv_nhwc_kernel(const ushort* __restrict__ x2, const ushort* __restrict__ w2,
                      float* __restrict__ out)
{
  // [row 0..127][64 bf16], 16B chunks XOR-swizzled: phys_chunk = chunk ^ (row&7)
  __shared__ alignas(16) ushort a_lds[128 * 64];   // A: rows = out-channel
  __shared__ alignas(16) ushort b_lds[128 * 64];   // B: rows = pixel

  const int tid  = threadIdx.x;
  const int lane = tid & 63;
  const int wid  = tid >> 6;
  const int wrow = wid >> 1;
  const int wcol = wid & 1;

  // ---- T1: bijective XCD chunk swizzle (m204), nwg=1922, co-fastest ----
  const int nwg = 1922, q8 = nwg >> 3, r8 = nwg & 7;   // 240, 2
  const int wg  = blockIdx.x;
  const int xcd = wg & 7, sidx = wg >> 3;
  const int logical = (xcd < r8 ? xcd * (q8 + 1) : r8 * (q8 + 1) + (xcd - r8) * q8) + sidx;
  const int co0 = (logical & 1) * 128;
  const int p0  = (logical >> 1) * 128;

  // ---------- staging geometry: wave stages rows [wid*32, wid*32+32) of each tile ----------
  const int lrow = lane >> 3;            // 0..7 row within 8-row group
  const int lc   = (lane & 7) ^ lrow;    // logical chunk this lane fetches (pre-swizzle)

  // B per-lane source base (pixel row fixed for whole kernel)
  const ushort* pB[4];
  #pragma unroll
  for (int i = 0; i < 4; ++i) {
    const int row   = wid * 32 + i * 8 + lrow;
    const int pglob = p0 + row;
    const int nimg  = pglob / PIXIMG;
    const int prem  = pglob - nimg * PIXIMG;
    const int oh    = prem / WO;
    const int ow    = prem - oh * WO;
    pB[i] = x2 + (size_t)((nimg * HIN + oh) * WIN + ow) * CI + lc * 8;
  }
  // A per-lane source base
  const ushort* pA = w2 + (size_t)(co0 + wid * 32 + lrow) * KTOT + lc * 8;

  // ---------- fragment read offsets (swizzle folded in) ----------
  const int frow_a = wrow * 64 + (lane & 15);
  const int frow_b = wcol * 64 + (lane & 15);
  int aoff[2], boff[2];
  #pragma unroll
  for (int kk = 0; kk < 2; ++kk) {
    const int chk = (kk * 4 + (lane >> 4)) ^ (lane & 7);
    aoff[kk] = frow_a * 64 + chk * 8;
    boff[kk] = frow_b * 64 + chk * 8;
  }

  f32x4 acc[4][4];
  #pragma unroll
  for (int i = 0; i < 4; ++i)
    #pragma unroll
    for (int j = 0; j < 4; ++j)
      acc[i][j] = (f32x4){0.f, 0.f, 0.f, 0.f};

  #pragma unroll
  for (int kt = 0; kt < NKT; ++kt) {
    if (kt) __syncthreads();   // previous compute done before overwriting LDS

    // tap = kt>>1 is wave-uniform AND compile-time (full unroll):
    const int tap   = kt >> 1;
    const int rr    = (tap * 11) >> 5;         // tap/3
    const int ss    = tap - rr * 3;
    const int coffB = (rr * WIN + ss) * CI + (kt & 1) * 64;
    const int coffA = kt * 64;

    #pragma unroll
    for (int i = 0; i < 4; ++i) {
      const ushort* src = pA + (size_t)i * (8 * KTOT) + coffA;
      __builtin_amdgcn_global_load_lds(
          (const __attribute__((address_space(1))) uint*)(const void*)src,
          (__attribute__((address_space(3))) uint*)(void*)&a_lds[wid * 2048 + i * 512],
          16, 0, 0);
    }
    #pragma unroll
    for (int i = 0; i < 4; ++i) {
      const ushort* src = pB[i] + coffB;
      __builtin_amdgcn_global_load_lds(
          (const __attribute__((address_space(1))) uint*)(const void*)src,
          (__attribute__((address_space(3))) uint*)(void*)&b_lds[wid * 2048 + i * 512],
          16, 0, 0);
    }

    __syncthreads();   // compiler drains vmcnt(0) here: tiles ready

    // ---- compute: 2 k-steps x 4x4 fragments ----
    #pragma unroll
    for (int kk = 0; kk < 2; ++kk) {
      bf16x8 af[4], bb[4];
      #pragma unroll
      for (int mi = 0; mi < 4; ++mi)
        af[mi] = *reinterpret_cast<const bf16x8*>(&a_lds[aoff[kk] + mi * (16 * 64)]);
      #pragma unroll
      for (int ni = 0; ni < 4; ++ni)
        bb[ni] = *reinterpret_cast<const bf16x8*>(&b_lds[boff[kk] + ni * (16 * 64)]);
      #pragma unroll
      for (int mi = 0; mi < 4; ++mi)
        #pragma unroll
        for (int ni = 0; ni < 4; ++ni)
          acc[mi][ni] = __builtin_amdgcn_mfma_f32_16x16x32_bf16(af[mi], bb[ni], acc[mi][ni], 0, 0, 0);
    }
  }

  // ---- epilogue ----
  #pragma unroll
  for (int ni = 0; ni < 4; ++ni) {
    const int pix = p0 + wcol * 64 + ni * 16 + (lane & 15);
    const int n2  = pix / PIXIMG;
    const int pr2 = pix - n2 * PIXIMG;
    float* ob = out + (size_t)n2 * (CO * PIXIMG) + pr2
                    + (size_t)(co0 + wrow * 64 + ((lane >> 4) * 4)) * PIXIMG;
    #pragma unroll
    for (int mi = 0; mi < 4; ++mi) {
      float* po = ob + (size_t)mi * (16 * PIXIMG);
      #pragma unroll
      for (int r = 0; r < 4; ++r)
        po[(size_t)r * PIXIMG] = acc[mi][ni][r];
    }
  }
}

// ---------------- fallback (tiny workspace): direct fp32 gather, reg-staged ----------------
__global__ __launch_bounds__(256, 3)
void conv_fallback_kernel(const float* __restrict__ x, const float* __restrict__ wt,
                          float* __restrict__ out)
{
  __shared__ alignas(16) ushort a_lds[128 * 64];
  __shared__ alignas(16) ushort b_lds[128 * 64];

  const int tid  = threadIdx.x;
  const int lane = tid & 63;
  const int wid  = tid >> 6;
  const int wrow = wid >> 1;
  const int wcol = wid & 1;
  const int co0 = blockIdx.x * 128;
  const int p0  = blockIdx.y * 128;

  const int pl    = tid & 127;
  const int kgsel = __builtin_amdgcn_readfirstlane(tid >> 7);
  const int pglob = p0 + pl;
  const int nimg  = pglob / PIXIMG;
  const int prem  = pglob - nimg * PIXIMG;
  const int oh    = prem / WO;
  const int ow    = prem - oh * WO;
  const int xpix  = nimg * XIMG + oh * WIN + ow;

  const int frow_a = wrow * 64 + (lane & 15);
  const int frow_b = wcol * 64 + (lane & 15);
  int aoff[2], boff[2];
  #pragma unroll
  for (int kk = 0; kk < 2; ++kk) {
    const int chk = (kk * 4 + (lane >> 4)) ^ (lane & 7);
    aoff[kk] = frow_a * 64 + chk * 8;
    boff[kk] = frow_b * 64 + chk * 8;
  }

  f32x4 acc[4][4];
  #pragma unroll
  for (int i = 0; i < 4; ++i)
    #pragma unroll
    for (int j = 0; j < 4; ++j)
      acc[i][j] = (f32x4){0.f, 0.f, 0.f, 0.f};

  for (int kt = 0; kt < NKT; ++kt) {
    const int k0 = kt * BK;   // old k-order: k = ci*9 + r*3 + s
    if (kt) __syncthreads();

    #pragma unroll
    for (int it = 0; it < 4; ++it) {
      const int kg = kgsel + it * 2;
      uint pk[4];
      #pragma unroll
      for (int j = 0; j < 8; ++j) {
        const int k  = k0 + kg * 8 + j;
        const int ci = k / 9;
        const int rs = k - ci * 9;
        const int r  = rs / 3;
        const int s  = rs - r * 3;
        const ushort u = f2bf(x[xpix + ci * (HIN * WIN) + r * WIN + s]);
        if (j & 1) pk[j >> 1] |= ((uint)u) << 16;
        else       pk[j >> 1]  = (uint)u;
      }
      uint4v q = {pk[0], pk[1], pk[2], pk[3]};
      *reinterpret_cast<uint4v*>(&b_lds[pl * 64 + ((kg ^ (pl & 7)) * 8)]) = q;
    }

    #pragma unroll
    for (int i = 0; i < 8; ++i) {
      const int id  = i * 256 + tid;
      const int row = id >> 4;
      const int c4  = id & 15;
      const float4 v = *reinterpret_cast<const float4*>(
          wt + (size_t)(co0 + row) * KTOT + k0 + c4 * 4);
      uint2v q;
      q[0] = (uint)f2bf(v.x) | ((uint)f2bf(v.y) << 16);
      q[1] = (uint)f2bf(v.z) | ((uint)f2bf(v.w) << 16);
      *reinterpret_cast<uint2v*>(
          &a_lds[row * 64 + (((c4 >> 1) ^ (row & 7)) * 8) + (c4 & 1) * 4]) = q;
    }

    __syncthreads();

    #pragma unroll
    for (int kk = 0; kk < 2; ++kk) {
      bf16x8 af[4], bb[4];
      #pragma unroll
      for (int mi = 0; mi < 4; ++mi)
        af[mi] = *reinterpret_cast<const bf16x8*>(&a_lds[aoff[kk] + mi * (16 * 64)]);
      #pragma unroll
      for (int ni = 0; ni < 4; ++ni)
        bb[ni] = *reinterpret_cast<const bf16x8*>(&b_lds[boff[kk] + ni * (16 * 64)]);
      #pragma unroll
      for (int mi = 0; mi < 4; ++mi)
        #pragma unroll
        for (int ni = 0; ni < 4; ++ni)
          acc[mi][ni] = __builtin_amdgcn_mfma_f32_16x16x32_bf16(af[mi], bb[ni], acc[mi][ni], 0, 0, 0);
    }
  }

  #pragma unroll
  for (int ni = 0; ni < 4; ++ni) {
    const int pix = p0 + wcol * 64 + ni * 16 + (lane & 15);
    const int n2  = pix / PIXIMG;
    const int pr2 = pix - n2 * PIXIMG;
    float* ob = out + (size_t)n2 * (CO * PIXIMG) + pr2
                    + (size_t)(co0 + wrow * 64 + ((lane >> 4) * 4)) * PIXIMG;
    #pragma unroll
    for (int mi = 0; mi < 4; ++mi) {
      float* po = ob + (size_t)mi * (16 * PIXIMG);
      #pragma unroll
      for (int r = 0; r < 4; ++r)
        po[(size_t)r * PIXIMG] = acc[mi][ni][r];
    }
  }
}

extern "C" void kernel_launch(void* const* d_in, const int* in_sizes, int n_in,
                              void* d_out, int out_size, void* d_ws, size_t ws_size,
                              hipStream_t stream) {
  const float* x  = (const float*)d_in[0];
  const float* wt = (const float*)d_in[1];
  float* out = (float*)d_out;

  ushort* w2 = (ushort*)d_ws;
  ushort* x2 = (ushort*)((char*)d_ws + 589824);

  const size_t need = 589824 + (size_t)NB * XIMG * 2;   // ~34.1 MB

  if (ws_size >= need) {
    repack_fused_kernel<<<dim3(2304), dim3(256), 0, stream>>>(x, wt, x2, w2);
    conv_nhwc_kernel<<<dim3(1922), dim3(256), 0, stream>>>(x2, w2, out);
  } else {
    conv_fallback_kernel<<<dim3(CO / 128, NPIX / 128), dim3(256), 0, stream>>>(x, wt, out);
  }
}

// Round 11
// 100.593 us; speedup vs baseline: 3.8053x; 3.8053x over previous
//
#include <hip/hip_runtime.h>
#include <hip/hip_bf16.h>

typedef unsigned short ushort;
typedef unsigned int uint;
typedef __bf16 bf16x8 __attribute__((ext_vector_type(8)));
typedef float f32x4 __attribute__((ext_vector_type(4)));
typedef uint uint4v __attribute__((ext_vector_type(4)));
typedef uint uint2v __attribute__((ext_vector_type(2)));

#define CI 128
#define HIN 64
#define WIN 64
#define CO 256
#define HO 62
#define WO 62
#define NB 32
#define KTOT 1152            // 9 taps * 128 ci   (k = tap*128 + ci in repacked order)
#define PIXIMG 3844          // 62*62
#define NPIX 123008          // 32*3844, divisible by 128
#define XIMG 524288          // 128*64*64
#define BK 64
#define NKT 18               // 1152/64

__device__ __forceinline__ ushort f2bf(float f) {
  uint u = __builtin_bit_cast(uint, f);
  u += 0x7fffu + ((u >> 16) & 1u);   // RNE; inputs are finite Gaussians
  return (ushort)(u >> 16);
}

// ---------------- fused prep ----------------
// blocks 0..2047:  x[n][ci][h][w] fp32 -> x2[n][h][w][ci] bf16   (n = b>>6, h = b&63)
// blocks 2048..2303: w[co][ci][3][3] fp32 -> w2[co][tap*128+ci] bf16 (co = b-2048)
#define XPAD 132   // floats per w-row in LDS; 132*4B = 16B-aligned rows
__global__ __launch_bounds__(256) void repack_fused_kernel(const float* __restrict__ x,
                                                           const float* __restrict__ w,
                                                           ushort* __restrict__ x2,
                                                           ushort* __restrict__ w2) {
  __shared__ float t[WIN * XPAD];           // 33792 B
  const int b   = blockIdx.x;
  const int tid = threadIdx.x;

  if (b >= 2048) {                          // ---- weight repack ----
    const int co = b - 2048;
    for (int idx = tid; idx < KTOT; idx += 256) {
      const int tp = idx >> 7;              // tap 0..8
      const int ci = idx & 127;
      w2[co * KTOT + idx] = f2bf(w[(co * CI + ci) * 9 + tp]);
    }
    return;
  }

  const int n = b >> 6;                     // 0..31
  const int h = b & 63;                     // 0..63
  const float* src = x + ((size_t)n * CI * HIN + h) * WIN;   // + ci*4096 + w
  #pragma unroll
  for (int it = 0; it < 8; ++it) {
    const int idx = it * 256 + tid;         // 0..2047
    const int ci  = idx >> 4;               // 0..127
    const int w4  = (idx & 15) * 4;         // 0..60
    const float4 v = *reinterpret_cast<const float4*>(src + (size_t)ci * (HIN * WIN) + w4);
    t[(w4 + 0) * XPAD + ci] = v.x;
    t[(w4 + 1) * XPAD + ci] = v.y;
    t[(w4 + 2) * XPAD + ci] = v.z;
    t[(w4 + 3) * XPAD + ci] = v.w;
  }
  __syncthreads();
  ushort* dst = x2 + ((size_t)(n * HIN + h) * WIN) * CI;
  #pragma unroll
  for (int it = 0; it < 4; ++it) {
    const int idx = it * 256 + tid;         // 0..1023
    const int wq  = idx >> 4;               // 0..63
    const int cig = idx & 15;               // 0..15
    const float* p = &t[wq * XPAD + cig * 8];
    uint4v q;
    q[0] = (uint)f2bf(p[0]) | ((uint)f2bf(p[1]) << 16);
    q[1] = (uint)f2bf(p[2]) | ((uint)f2bf(p[3]) << 16);
    q[2] = (uint)f2bf(p[4]) | ((uint)f2bf(p[5]) << 16);
    q[3] = (uint)f2bf(p[6]) | ((uint)f2bf(p[7]) << 16);
    *reinterpret_cast<uint4v*>(dst + (size_t)wq * CI + cig * 8) = q;
  }
}

// ---------------- main: implicit GEMM, all staging via global_load_lds (R4 structure) ----
// __launch_bounds__(256,4): 64 VGPR + 64 AGPR = 128 unified regs/wave x 4 waves/SIMD = 512
// (exact fit; 5 waves/SIMD would need 640 > 512 -> acc spill, the R10 failure).
__global__ __launch_bounds__(256, 4)
void conv_nhwc_kernel(const ushort* __restrict__ x2, const ushort* __restrict__ w2,
                      float* __restrict__ out)
{
  // [row 0..127][64 bf16], 16B chunks XOR-swizzled: phys_chunk = chunk ^ (row&7)
  __shared__ alignas(16) ushort a_lds[128 * 64];   // A: rows = out-channel
  __shared__ alignas(16) ushort b_lds[128 * 64];   // B: rows = pixel

  const int tid  = threadIdx.x;
  const int lane = tid & 63;
  const int wid  = tid >> 6;
  const int wrow = wid >> 1;
  const int wcol = wid & 1;

  // ---- T1: bijective XCD chunk swizzle (m204), nwg=1922, co-fastest ----
  const int nwg = 1922, q8 = nwg >> 3, r8 = nwg & 7;   // 240, 2
  const int wg  = blockIdx.x;
  const int xcd = wg & 7, sidx = wg >> 3;
  const int logical = (xcd < r8 ? xcd * (q8 + 1) : r8 * (q8 + 1) + (xcd - r8) * q8) + sidx;
  const int co0 = (logical & 1) * 128;
  const int p0  = (logical >> 1) * 128;

  // ---------- staging geometry: wave stages rows [wid*32, wid*32+32) of each tile ----------
  const int lrow = lane >> 3;            // 0..7 row within 8-row group
  const int lc   = (lane & 7) ^ lrow;    // logical chunk this lane fetches (pre-swizzle)

  // B per-lane source base (pixel row fixed for whole kernel)
  const ushort* pB[4];
  #pragma unroll
  for (int i = 0; i < 4; ++i) {
    const int row   = wid * 32 + i * 8 + lrow;
    const int pglob = p0 + row;
    const int nimg  = pglob / PIXIMG;
    const int prem  = pglob - nimg * PIXIMG;
    const int oh    = prem / WO;
    const int ow    = prem - oh * WO;
    pB[i] = x2 + (size_t)((nimg * HIN + oh) * WIN + ow) * CI + lc * 8;
  }
  // A per-lane source base
  const ushort* pA = w2 + (size_t)(co0 + wid * 32 + lrow) * KTOT + lc * 8;

  // ---------- fragment read offsets (swizzle folded in) ----------
  const int frow_a = wrow * 64 + (lane & 15);
  const int frow_b = wcol * 64 + (lane & 15);
  int aoff[2], boff[2];
  #pragma unroll
  for (int kk = 0; kk < 2; ++kk) {
    const int chk = (kk * 4 + (lane >> 4)) ^ (lane & 7);
    aoff[kk] = frow_a * 64 + chk * 8;
    boff[kk] = frow_b * 64 + chk * 8;
  }

  f32x4 acc[4][4];
  #pragma unroll
  for (int i = 0; i < 4; ++i)
    #pragma unroll
    for (int j = 0; j < 4; ++j)
      acc[i][j] = (f32x4){0.f, 0.f, 0.f, 0.f};

  #pragma unroll
  for (int kt = 0; kt < NKT; ++kt) {
    if (kt) __syncthreads();   // previous compute done before overwriting LDS

    // tap = kt>>1 is wave-uniform AND compile-time (full unroll):
    const int tap   = kt >> 1;
    const int rr    = (tap * 11) >> 5;         // tap/3
    const int ss    = tap - rr * 3;
    const int coffB = (rr * WIN + ss) * CI + (kt & 1) * 64;
    const int coffA = kt * 64;

    #pragma unroll
    for (int i = 0; i < 4; ++i) {
      const ushort* src = pA + (size_t)i * (8 * KTOT) + coffA;
      __builtin_amdgcn_global_load_lds(
          (const __attribute__((address_space(1))) uint*)(const void*)src,
          (__attribute__((address_space(3))) uint*)(void*)&a_lds[wid * 2048 + i * 512],
          16, 0, 0);
    }
    #pragma unroll
    for (int i = 0; i < 4; ++i) {
      const ushort* src = pB[i] + coffB;
      __builtin_amdgcn_global_load_lds(
          (const __attribute__((address_space(1))) uint*)(const void*)src,
          (__attribute__((address_space(3))) uint*)(void*)&b_lds[wid * 2048 + i * 512],
          16, 0, 0);
    }

    __syncthreads();   // compiler drains vmcnt(0) here: tiles ready

    // ---- compute: 2 k-steps x 4x4 fragments ----
    #pragma unroll
    for (int kk = 0; kk < 2; ++kk) {
      bf16x8 af[4], bb[4];
      #pragma unroll
      for (int mi = 0; mi < 4; ++mi)
        af[mi] = *reinterpret_cast<const bf16x8*>(&a_lds[aoff[kk] + mi * (16 * 64)]);
      #pragma unroll
      for (int ni = 0; ni < 4; ++ni)
        bb[ni] = *reinterpret_cast<const bf16x8*>(&b_lds[boff[kk] + ni * (16 * 64)]);
      #pragma unroll
      for (int mi = 0; mi < 4; ++mi)
        #pragma unroll
        for (int ni = 0; ni < 4; ++ni)
          acc[mi][ni] = __builtin_amdgcn_mfma_f32_16x16x32_bf16(af[mi], bb[ni], acc[mi][ni], 0, 0, 0);
    }
  }

  // ---- epilogue ----
  #pragma unroll
  for (int ni = 0; ni < 4; ++ni) {
    const int pix = p0 + wcol * 64 + ni * 16 + (lane & 15);
    const int n2  = pix / PIXIMG;
    const int pr2 = pix - n2 * PIXIMG;
    float* ob = out + (size_t)n2 * (CO * PIXIMG) + pr2
                    + (size_t)(co0 + wrow * 64 + ((lane >> 4) * 4)) * PIXIMG;
    #pragma unroll
    for (int mi = 0; mi < 4; ++mi) {
      float* po = ob + (size_t)mi * (16 * PIXIMG);
      #pragma unroll
      for (int r = 0; r < 4; ++r)
        po[(size_t)r * PIXIMG] = acc[mi][ni][r];
    }
  }
}

// ---------------- fallback (tiny workspace): direct fp32 gather, reg-staged ----------------
__global__ __launch_bounds__(256, 3)
void conv_fallback_kernel(const float* __restrict__ x, const float* __restrict__ wt,
                          float* __restrict__ out)
{
  __shared__ alignas(16) ushort a_lds[128 * 64];
  __shared__ alignas(16) ushort b_lds[128 * 64];

  const int tid  = threadIdx.x;
  const int lane = tid & 63;
  const int wid  = tid >> 6;
  const int wrow = wid >> 1;
  const int wcol = wid & 1;
  const int co0 = blockIdx.x * 128;
  const int p0  = blockIdx.y * 128;

  const int pl    = tid & 127;
  const int kgsel = __builtin_amdgcn_readfirstlane(tid >> 7);
  const int pglob = p0 + pl;
  const int nimg  = pglob / PIXIMG;
  const int prem  = pglob - nimg * PIXIMG;
  const int oh    = prem / WO;
  const int ow    = prem - oh * WO;
  const int xpix  = nimg * XIMG + oh * WIN + ow;

  const int frow_a = wrow * 64 + (lane & 15);
  const int frow_b = wcol * 64 + (lane & 15);
  int aoff[2], boff[2];
  #pragma unroll
  for (int kk = 0; kk < 2; ++kk) {
    const int chk = (kk * 4 + (lane >> 4)) ^ (lane & 7);
    aoff[kk] = frow_a * 64 + chk * 8;
    boff[kk] = frow_b * 64 + chk * 8;
  }

  f32x4 acc[4][4];
  #pragma unroll
  for (int i = 0; i < 4; ++i)
    #pragma unroll
    for (int j = 0; j < 4; ++j)
      acc[i][j] = (f32x4){0.f, 0.f, 0.f, 0.f};

  for (int kt = 0; kt < NKT; ++kt) {
    const int k0 = kt * BK;   // old k-order: k = ci*9 + r*3 + s
    if (kt) __syncthreads();

    #pragma unroll
    for (int it = 0; it < 4; ++it) {
      const int kg = kgsel + it * 2;
      uint pk[4];
      #pragma unroll
      for (int j = 0; j < 8; ++j) {
        const int k  = k0 + kg * 8 + j;
        const int ci = k / 9;
        const int rs = k - ci * 9;
        const int r  = rs / 3;
        const int s  = rs - r * 3;
        const ushort u = f2bf(x[xpix + ci * (HIN * WIN) + r * WIN + s]);
        if (j & 1) pk[j >> 1] |= ((uint)u) << 16;
        else       pk[j >> 1]  = (uint)u;
      }
      uint4v q = {pk[0], pk[1], pk[2], pk[3]};
      *reinterpret_cast<uint4v*>(&b_lds[pl * 64 + ((kg ^ (pl & 7)) * 8)]) = q;
    }

    #pragma unroll
    for (int i = 0; i < 8; ++i) {
      const int id  = i * 256 + tid;
      const int row = id >> 4;
      const int c4  = id & 15;
      const float4 v = *reinterpret_cast<const float4*>(
          wt + (size_t)(co0 + row) * KTOT + k0 + c4 * 4);
      uint2v q;
      q[0] = (uint)f2bf(v.x) | ((uint)f2bf(v.y) << 16);
      q[1] = (uint)f2bf(v.z) | ((uint)f2bf(v.w) << 16);
      *reinterpret_cast<uint2v*>(
          &a_lds[row * 64 + (((c4 >> 1) ^ (row & 7)) * 8) + (c4 & 1) * 4]) = q;
    }

    __syncthreads();

    #pragma unroll
    for (int kk = 0; kk < 2; ++kk) {
      bf16x8 af[4], bb[4];
      #pragma unroll
      for (int mi = 0; mi < 4; ++mi)
        af[mi] = *reinterpret_cast<const bf16x8*>(&a_lds[aoff[kk] + mi * (16 * 64)]);
      #pragma unroll
      for (int ni = 0; ni < 4; ++ni)
        bb[ni] = *reinterpret_cast<const bf16x8*>(&b_lds[boff[kk] + ni * (16 * 64)]);
      #pragma unroll
      for (int mi = 0; mi < 4; ++mi)
        #pragma unroll
        for (int ni = 0; ni < 4; ++ni)
          acc[mi][ni] = __builtin_amdgcn_mfma_f32_16x16x32_bf16(af[mi], bb[ni], acc[mi][ni], 0, 0, 0);
    }
  }

  #pragma unroll
  for (int ni = 0; ni < 4; ++ni) {
    const int pix = p0 + wcol * 64 + ni * 16 + (lane & 15);
    const int n2  = pix / PIXIMG;
    const int pr2 = pix - n2 * PIXIMG;
    float* ob = out + (size_t)n2 * (CO * PIXIMG) + pr2
                    + (size_t)(co0 + wrow * 64 + ((lane >> 4) * 4)) * PIXIMG;
    #pragma unroll
    for (int mi = 0; mi < 4; ++mi) {
      float* po = ob + (size_t)mi * (16 * PIXIMG);
      #pragma unroll
      for (int r = 0; r < 4; ++r)
        po[(size_t)r * PIXIMG] = acc[mi][ni][r];
    }
  }
}

extern "C" void kernel_launch(void* const* d_in, const int* in_sizes, int n_in,
                              void* d_out, int out_size, void* d_ws, size_t ws_size,
                              hipStream_t stream) {
  const float* x  = (const float*)d_in[0];
  const float* wt = (const float*)d_in[1];
  float* out = (float*)d_out;

  ushort* w2 = (ushort*)d_ws;
  ushort* x2 = (ushort*)((char*)d_ws + 589824);

  const size_t need = 589824 + (size_t)NB * XIMG * 2;   // ~34.1 MB

  if (ws_size >= need) {
    repack_fused_kernel<<<dim3(2304), dim3(256), 0, stream>>>(x, wt, x2, w2);
    conv_nhwc_kernel<<<dim3(1922), dim3(256), 0, stream>>>(x2, w2, out);
  } else {
    conv_fallback_kernel<<<dim3(CO / 128, NPIX / 128), dim3(256), 0, stream>>>(x, wt, out);
  }
}